// Round 14
// baseline (648.500 us; speedup 1.0000x reference)
//
#include <hip/hip_runtime.h>
#include <hip/hip_bf16.h>

// Problem constants
#define N_NODES 10000
#define N_EDGES 64000
#define IN_F    1247
#define KPAD    1280   // IN_F padded to mult of 32
#define NH      4
#define D0      256
#define D1      8
#define HD0     1024   // NH*D0
#define HD1     32     // NH*D1
#define NBIG    3072   // Wl0 | Wr0 | Wres0
#define NBIG3   3328   // + 32 z cols + pad to 13*256
#define OUTF    6
#define INV_N   (1.0f / 10000.0f)
#define MPAD    10240  // 80 row-tiles (XCD swizzle: 80 = 8 XCD * 10)

typedef __attribute__((ext_vector_type(8))) short bf16x8;
typedef __attribute__((ext_vector_type(4))) float f32x4;
typedef unsigned int u32;

// async 16B global -> LDS (DMA). LDS dest: wave-uniform base + lane*16.
__device__ __forceinline__ void async_copy16(const unsigned short* gsrc,
                                             unsigned short* ldst) {
    __builtin_amdgcn_global_load_lds(
        (const __attribute__((address_space(1))) u32*)(gsrc),
        (__attribute__((address_space(3))) u32*)(ldst), 16, 0, 0);
}

// ---------------- workspace layout (float-slot offsets) ----------------
constexpr size_t OFF_FLAG   = 0;                          // 16
constexpr size_t OFF_COLSUM = 16;                         // 1280
constexpr size_t OFF_MASKM  = 1296;                       // 1280
constexpr size_t OFF_Z      = 2576;                       // N*32
constexpr size_t OFF_H3     = OFF_Z    + 320000;          // N*32
constexpr size_t OFF_OUT0   = OFF_H3   + 320000;          // bf16 N*1024 (res+bias)
constexpr size_t OFF_FS1    = OFF_OUT0 + 10240000;        // N*32
constexpr size_t OFF_FD1    = OFF_FS1  + 320000;          // N*32
constexpr size_t OFF_OUT1   = OFF_FD1  + 320000;          // N*32
constexpr size_t OFF_B0F    = OFF_OUT1 + 320000;          // 1024
constexpr size_t OFF_B1F    = OFF_B0F  + 1024;            // 64
constexpr size_t OFF_DEG    = OFF_B1F  + 64;              // int 10016
constexpr size_t OFF_ROWPTR = OFF_DEG  + 10016;           // int 10016
constexpr size_t OFF_CURSOR = OFF_ROWPTR + 10016;         // int 10016
constexpr size_t OFF_CSRE   = OFF_CURSOR + 10016;         // int 64000
constexpr size_t OFF_FS0B   = OFF_CSRE + 64000;           // bf16 N*1024
constexpr size_t OFF_FD0B   = OFF_FS0B + 5120000;         // bf16 N*1024 (reused as out0b)
constexpr size_t OFF_ABF    = OFF_FD0B + 5120000;         // bf16 MPAD*KPAD
constexpr size_t OFF_BT     = OFF_ABF  + 6553600;         // bf16 NBIG3*KPAD
constexpr size_t OFF_BT1    = OFF_BT   + 2129920;         // bf16 96*1024
constexpr size_t WS_FLOATS  = OFF_BT1  + 49152;

// dual-dtype load: is_f32 ? float : bf16
__device__ __forceinline__ float ldin(const void* p, size_t i, int f32) {
    return f32 ? ((const float*)p)[i]
               : __bfloat162float(((const __hip_bfloat16*)p)[i]);
}
__device__ __forceinline__ float bfu2f(unsigned short u) {
    union { unsigned int i; float f; } x;
    x.i = ((unsigned int)u) << 16;
    return x.f;
}
__device__ __forceinline__ unsigned short f2bu(float v) {
    __hip_bfloat16 h = __float2bfloat16(v);
    unsigned short u;
    __builtin_memcpy(&u, &h, 2);
    return u;
}

// ---------------- kernels ----------------

// fused init: detect dtype (64) + zero deg (40) + zero bt pad rows 3104..3327 (560)
__global__ void init_kernel(const unsigned short* __restrict__ feats_w,
                            int* __restrict__ flag, int* __restrict__ deg,
                            u32* __restrict__ btpad) {
    int b = blockIdx.x, t = threadIdx.x;
    if (b < 64) {
        int found = 0;
        for (int i = b * 256 + t; i < 131072; i += 64 * 256)
            if (((feats_w[i] >> 7) & 0xFF) == 0xFF) found = 1;
        if (found) atomicOr(flag, 1);
    } else if (b < 104) {
        int idx = (b - 64) * 256 + t;
        if (idx < N_NODES + 16) deg[idx] = 0;
    } else {
        int idx = (b - 104) * 256 + t;
        if (idx < 143360) btpad[idx] = 0;   // 224 rows * 1280 * 2B as u32
    }
}

// fused: colsum (200 blocks) + deg histogram (250) + smallprep (5)
__global__ void prepA_kernel(const void* __restrict__ feats, const int* __restrict__ dst,
                             const void* __restrict__ tm, const void* __restrict__ am,
                             const void* __restrict__ vm, const void* __restrict__ b0,
                             const void* __restrict__ b1,
                             float* __restrict__ colsum, int* __restrict__ deg,
                             float* __restrict__ maskmul, float* __restrict__ b0f,
                             float* __restrict__ b1f, const int* __restrict__ dflag) {
    int b = blockIdx.x, t = threadIdx.x;
    if (b < 200) {
        int f32 = *dflag;
        int c = (b % 5) * 256 + t;
        if (c >= IN_F) return;
        int r0 = (b / 5) * 250;
        float s = 0.f;
        for (int r = r0; r < r0 + 250; ++r)
            s += ldin(feats, (size_t)r * IN_F + c, f32);
        atomicAdd(&colsum[c], s);
    } else if (b < 450) {
        int e = (b - 200) * 256 + t;
        if (e < N_EDGES) atomicAdd(&deg[dst[e]], 1);
    } else {
        int f32 = *dflag;
        int c = (b - 450) * 256 + t;
        if (c < IN_F) maskmul[c] = ldin(tm, c, f32) + ldin(am, c, f32) + ldin(vm, c, f32);
        if (c < HD0) b0f[c] = ldin(b0, c, f32);
        if (c < HD1) b1f[c] = ldin(b1, c, f32);
    }
}

__global__ __launch_bounds__(256) void scan_kernel(const int* __restrict__ deg,
                                                   int* __restrict__ rowptr,
                                                   int* __restrict__ cursor) {
    __shared__ int sums[256];
    __shared__ int offs[257];
    int t = threadIdx.x;
    int base = t * 40;
    int s = 0;
    for (int i = 0; i < 40; ++i) {
        int idx = base + i;
        if (idx < N_NODES) s += deg[idx];
    }
    sums[t] = s;
    __syncthreads();
    if (t == 0) {
        int run = 0;
        for (int i = 0; i < 256; ++i) { offs[i] = run; run += sums[i]; }
        offs[256] = run;
    }
    __syncthreads();
    int run = offs[t];
    for (int i = 0; i < 40; ++i) {
        int idx = base + i;
        if (idx < N_NODES) {
            rowptr[idx] = run; cursor[idx] = run;
            run += deg[idx];
        }
    }
    if (t == 255) rowptr[N_NODES] = offs[256];
}

__global__ void scatter_kernel(const int* __restrict__ dst, int* __restrict__ cursor,
                               int* __restrict__ csr_eid) {
    int e = blockIdx.x * 256 + threadIdx.x;
    if (e >= N_EDGES) return;
    int pos = atomicAdd(&cursor[dst[e]], 1);
    csr_eid[pos] = e;
}

// fused big prep: prep_row (10240) + bt transpose (3840) + w2cols (160) + bt1 (384)
__global__ __launch_bounds__(256) void prepB_kernel(
        const void* __restrict__ feats, const float* __restrict__ colsum,
        const float* __restrict__ maskmul, __hip_bfloat16* __restrict__ abf,
        const void* __restrict__ Wl0, const void* __restrict__ Wr0,
        const void* __restrict__ Wres0, const void* __restrict__ W2,
        __hip_bfloat16* __restrict__ bt,
        const void* __restrict__ Wl1, const void* __restrict__ Wr1,
        const void* __restrict__ Wres1, __hip_bfloat16* __restrict__ bt1,
        const int* __restrict__ dflag) {
    __shared__ float smem[1503];
    int b = blockIdx.x, t = threadIdx.x;
    int f32 = *dflag;
    if (b < MPAD) {
        int n = b;
        if (n >= N_NODES) {
            for (int k = t; k < KPAD; k += 256)
                abf[(size_t)n * KPAD + k] = __float2bfloat16(0.f);
            return;
        }
        float* rowbuf = smem;            // 1247
        float* red    = smem + IN_F;     // 256
        float s = 0.f;
        for (int c = t; c < IN_F; c += 256) {
            float f = ldin(feats, (size_t)n * IN_F + c, f32);
            float v = (f != 0.0f) ? f : 0.5f * colsum[c] * INV_N;   // 0.5*(h+h1)
            rowbuf[c] = v;
            s += fabsf(v);
        }
        red[t] = s;
        __syncthreads();
        for (int st = 128; st > 0; st >>= 1) {
            if (t < st) red[t] += red[t + st];
            __syncthreads();
        }
        float scale = 1.0f / fmaxf(red[0], 1e-12f);
        for (int k = t; k < KPAD; k += 256) {
            float v = (k < IN_F) ? rowbuf[k] * scale * maskmul[k] : 0.f;
            abf[(size_t)n * KPAD + k] = __float2bfloat16(v);
        }
    } else if (b < MPAD + 3840) {
        int b2 = b - MPAD;
        int bz = b2 / 1280, rem = b2 - bz * 1280;
        int by = rem >> 5, bx = rem & 31;
        float (*tile)[33] = (float(*)[33])smem;
        int n0 = bx * 32, k0 = by * 32;
        const void* W = (bz == 0) ? Wl0 : (bz == 1) ? Wr0 : Wres0;
        int tx = t & 31, ty = t >> 5;
        for (int i = ty; i < 32; i += 8) {
            int k = k0 + i;
            tile[i][tx] = (k < IN_F) ? ldin(W, (size_t)k * HD0 + n0 + tx, f32) : 0.f;
        }
        __syncthreads();
        for (int i = ty; i < 32; i += 8)
            bt[(size_t)(bz * 1024 + n0 + i) * KPAD + k0 + tx] = __float2bfloat16(tile[tx][i]);
    } else if (b < MPAD + 3840 + 160) {
        int idx = (b - (MPAD + 3840)) * 256 + t;
        if (idx >= 32 * KPAD) return;
        int n = idx / KPAD, k = idx % KPAD;
        int hh = n >> 3, o = n & 7;
        float v = (k < IN_F) ? ldin(W2, ((size_t)hh * IN_F + k) * D1 + o, f32) : 0.f;
        bt[(size_t)(NBIG + n) * KPAD + k] = __float2bfloat16(v);
    } else {
        int idx = (b - (MPAD + 4000)) * 256 + t;
        if (idx >= 96 * HD0) return;
        int n = idx >> 10, k = idx & 1023;
        int seg = n >> 5, col = n & 31;
        const void* W = (seg == 0) ? Wl1 : (seg == 1) ? Wr1 : Wres1;
        bt1[idx] = __float2bfloat16(ldin(W, (size_t)k * HD1 + col, f32));
    }
}

// MFMA GEMM: C[MPAD x 3328] = abf @ bt^T. 128x256 tile (B staged once serves 2x
// output -> 25% less vmem traffic vs 128x128), BK=32 single buffer (24KB LDS),
// fragment-major. XCD swizzle: flat grid 1040 = 8 XCD * (13 cols * 10 rows).
// Epilogue segments per 1024 cols: fs0b / fd0b / out0r(+b0) / z (gnl<32).
__global__ __launch_bounds__(256) void mfma_gemm(
        const unsigned short* __restrict__ A, const unsigned short* __restrict__ BT,
        const float* __restrict__ b0f, __hip_bfloat16* __restrict__ fs0b,
        __hip_bfloat16* __restrict__ fd0b, __hip_bfloat16* __restrict__ out0r,
        float* __restrict__ z) {
    __shared__ unsigned short As[8 * 512];    // 8KB:  128 rows x 32k
    __shared__ unsigned short Bs[16 * 512];   // 16KB: 256 cols x 32k
    const int g = blockIdx.x;
    const int xcd = g & 7, l = g >> 3;
    const int colb = l / 10, rowl = l - colb * 10;
    const int bm = (xcd * 10 + rowl) * 128;
    const int bn = colb * 256;
    const int tid = threadIdx.x;
    const int wave = tid >> 6, lane = tid & 63;
    const int quad = lane >> 4, l16 = lane & 15;
    const int wm = (wave & 1) * 64, wn = (wave >> 1) * 128;
    const int srow = lane & 15;
    const int skc  = (lane >> 4) * 8;
    const int NIT = KPAD / 32;   // 40

    f32x4 acc[4][8];
#pragma unroll
    for (int i = 0; i < 4; ++i)
#pragma unroll
        for (int j = 0; j < 8; ++j) acc[i][j] = (f32x4){0.f, 0.f, 0.f, 0.f};

#define STAGE(kk) do {                                                           \
        _Pragma("unroll")                                                        \
        for (int t = 0; t < 2; ++t) {                                            \
            int f = wave * 2 + t;                                                \
            async_copy16(A + (size_t)(bm + f * 16 + srow) * KPAD + (kk) + skc,   \
                         As + f * 512);                                          \
        }                                                                        \
        _Pragma("unroll")                                                        \
        for (int t = 0; t < 4; ++t) {                                            \
            int f = wave * 4 + t;                                                \
            async_copy16(BT + (size_t)(bn + f * 16 + srow) * KPAD + (kk) + skc,  \
                         Bs + f * 512);                                          \
        } } while (0)

    STAGE(0);
    for (int it = 0; it < NIT; ++it) {
        asm volatile("s_waitcnt vmcnt(0)" ::: "memory");
        asm volatile("s_barrier" ::: "memory");   // all deposits of this tile in
        bf16x8 af[4];
#pragma unroll
        for (int i = 0; i < 4; ++i)
            af[i] = *(const bf16x8*)(As + (((wave & 1) * 4 + i)) * 512 + lane * 8);
#pragma unroll
        for (int j = 0; j < 8; ++j) {
            bf16x8 bfr = *(const bf16x8*)(Bs + (((wave >> 1) * 8 + j)) * 512 + lane * 8);
#pragma unroll
            for (int i = 0; i < 4; ++i)
                acc[i][j] = __builtin_amdgcn_mfma_f32_16x16x32_bf16(
                    af[i], bfr, acc[i][j], 0, 0, 0);
        }
        asm volatile("s_barrier" ::: "memory");   // reads done; safe to overwrite
        if (it + 1 < NIT) STAGE((it + 1) * 32);
    }
#undef STAGE

    const int seg = bn >> 10;                 // 256-wide blocks never straddle segs
#pragma unroll
    for (int i = 0; i < 4; ++i) {
#pragma unroll
        for (int r = 0; r < 4; ++r) {
            int gm = bm + wm + i * 16 + quad * 4 + r;
            if (gm >= N_NODES) continue;
#pragma unroll
            for (int j = 0; j < 8; ++j) {
                int gnl = (bn & 1023) + wn + j * 16 + l16;
                float v = acc[i][j][r];
                if (seg == 0)      fs0b[(size_t)gm * HD0 + gnl] = __float2bfloat16(v);
                else if (seg == 1) fd0b[(size_t)gm * HD0 + gnl] = __float2bfloat16(v);
                else if (seg == 2) out0r[(size_t)gm * HD0 + gnl] = __float2bfloat16(v + b0f[gnl]);
                else if (gnl < HD1) z[(size_t)gm * HD1 + gnl] = v;
            }
        }
    }
}

// gat_inner fused attention (es/ed on the fly), 8 nodes per 256-block
__global__ __launch_bounds__(256) void att32z_kernel(
        const int* __restrict__ rowptr, const int* __restrict__ csre,
        const int* __restrict__ src, const float* __restrict__ z,
        const void* __restrict__ a2, float* __restrict__ h3,
        const int* __restrict__ dflag) {
    int f32 = *dflag;
    int n = blockIdx.x * 8 + (threadIdx.x >> 5);
    int lane = threadIdx.x & 31;
    int h = lane >> 3, o = lane & 7;
    float a2e = ldin(a2, h * 2 * D1 + o, f32);
    float a2d = ldin(a2, h * 2 * D1 + D1 + o, f32);
    float zn = z[(size_t)n * HD1 + lane];
    float edn = zn * a2d;
    edn += __shfl_xor(edn, 1); edn += __shfl_xor(edn, 2); edn += __shfl_xor(edn, 4);
    float den = 0.f, acc = 0.f;
    int start = rowptr[n], end = rowptr[n + 1];
    for (int i = start; i < end; ++i) {
        int s = src[csre[i]];
        float zs = z[(size_t)s * HD1 + lane];
        float esv = zs * a2e;
        esv += __shfl_xor(esv, 1); esv += __shfl_xor(esv, 2); esv += __shfl_xor(esv, 4);
        float x = esv + edn;
        x = x > 0.f ? x : 0.2f * x;
        float p = expf(x);
        den += p;
        acc += p * zs;
    }
    h3[(size_t)n * HD1 + lane] = acc / fmaxf(den, 1e-9f);
}

// fused layer-0 attention, single pass, src indices cached in LDS.
__global__ __launch_bounds__(256) void att0_kernel(
        const int* __restrict__ rowptr, const int* __restrict__ csre,
        const int* __restrict__ src, const __hip_bfloat16* __restrict__ fs,
        const __hip_bfloat16* __restrict__ fd, const void* __restrict__ a0,
        const __hip_bfloat16* __restrict__ out0res, __hip_bfloat16* __restrict__ out0b,
        const int* __restrict__ dflag) {
    int f32 = *dflag;
    int n = blockIdx.x;
    int t = threadIdx.x;
    __shared__ float sfd[HD0];
    __shared__ float sa0[HD0];
    __shared__ int sidx[128];
    int start = rowptr[n], end = rowptr[n + 1];
    int deg = end - start;
    {
        const unsigned short* fdp = (const unsigned short*)fd + (size_t)n * HD0;
        ushort4 u = *(const ushort4*)(fdp + 4 * t);
        sfd[4 * t + 0] = bfu2f(u.x); sfd[4 * t + 1] = bfu2f(u.y);
        sfd[4 * t + 2] = bfu2f(u.z); sfd[4 * t + 3] = bfu2f(u.w);
#pragma unroll
        for (int i = 0; i < 4; ++i) sa0[4 * t + i] = ldin(a0, 4 * t + i, f32);
        if (t < deg && t < 128) sidx[t] = src[csre[start + t]];
    }
    __syncthreads();
    const unsigned short* fsu = (const unsigned short*)fs;
    float den = 0.f;
    float acc[4] = {0.f, 0.f, 0.f, 0.f};
#pragma unroll 2
    for (int i = 0; i < deg; ++i) {
        int s = (i < 128) ? sidx[i] : src[csre[start + i]];
        ushort4 u = *(const ushort4*)(fsu + (size_t)s * HD0 + 4 * t);
        float fv[4], part = 0.f;
#pragma unroll
        for (int j = 0; j < 4; ++j) {
            unsigned short uj = (j == 0) ? u.x : (j == 1) ? u.y : (j == 2) ? u.z : u.w;
            fv[j] = bfu2f(uj);
            float x = fv[j] + sfd[4 * t + j];
            x = x > 0.f ? x : 0.2f * x;
            part += x * sa0[4 * t + j];
        }
        for (int off = 32; off > 0; off >>= 1) part += __shfl_xor(part, off);
        float p = expf(part);
        den += p;   // identical across the wave (= head)
#pragma unroll
        for (int j = 0; j < 4; ++j) acc[j] += p * fv[j];
    }
    float inv = 1.0f / fmaxf(den, 1e-9f);
    ushort4 ub = *(const ushort4*)((const unsigned short*)out0res + (size_t)n * HD0 + 4 * t);
    ushort4 o;
    o.x = f2bu(fmaxf(bfu2f(ub.x) + acc[0] * inv, 0.f));
    o.y = f2bu(fmaxf(bfu2f(ub.y) + acc[1] * inv, 0.f));
    o.z = f2bu(fmaxf(bfu2f(ub.z) + acc[2] * inv, 0.f));
    o.w = f2bu(fmaxf(bfu2f(ub.w) + acc[3] * inv, 0.f));
    *(ushort4*)((unsigned short*)out0b + (size_t)n * HD0 + 4 * t) = o;
}

// layer-1 fused MFMA GEMM: C[10000 x 96] = out0b @ bt1^T, K=1024, 64-row tiles
__global__ __launch_bounds__(256) void mfma_gemm96(
        const unsigned short* __restrict__ A, const unsigned short* __restrict__ BT1,
        const float* __restrict__ b1f, float* __restrict__ fs1,
        float* __restrict__ fd1, float* __restrict__ out1) {
    __shared__ unsigned short As0[2048], Bs0[3072], As1[2048], Bs1[3072];  // 20KB
    const int tid = threadIdx.x;
    const int wave = tid >> 6, lane = tid & 63;
    const int quad = lane >> 4, l16 = lane & 15;
    const int bm = blockIdx.x * 64;
    const int srow = lane & 15;
    const int skc  = (lane >> 4) * 8;
    const int NIT = HD0 / 32;   // 32 (even)

    f32x4 acc[6];
#pragma unroll
    for (int j = 0; j < 6; ++j) acc[j] = (f32x4){0.f, 0.f, 0.f, 0.f};

#define STAGE96(kk, Adst, Bdst) do {                                              \
        async_copy16(A + (size_t)(bm + wave * 16 + srow) * HD0 + (kk) + skc,      \
                     (Adst) + wave * 512);                                        \
        async_copy16(BT1 + (size_t)(wave * 16 + srow) * HD0 + (kk) + skc,         \
                     (Bdst) + wave * 512);                                        \
        if (wave < 2)                                                             \
            async_copy16(BT1 + (size_t)((4 + wave) * 16 + srow) * HD0 + (kk) + skc, \
                         (Bdst) + (4 + wave) * 512);                              \
        } while (0)

#define COMPUTE96(Asrc, Bsrc) do {                                                \
        bf16x8 af = *(const bf16x8*)((Asrc) + wave * 512 + lane * 8);             \
        _Pragma("unroll")                                                         \
        for (int j = 0; j < 6; ++j) {                                             \
            bf16x8 bfr = *(const bf16x8*)((Bsrc) + j * 512 + lane * 8);           \
            acc[j] = __builtin_amdgcn_mfma_f32_16x16x32_bf16(af, bfr, acc[j], 0, 0, 0); \
        } } while (0)

    STAGE96(0, As0, Bs0);
    for (int it = 0; it < NIT; it += 2) {
        asm volatile("s_waitcnt vmcnt(0)" ::: "memory");
        asm volatile("s_barrier" ::: "memory");
        STAGE96((it + 1) * 32, As1, Bs1);
        COMPUTE96(As0, Bs0);
        asm volatile("s_waitcnt vmcnt(0)" ::: "memory");
        asm volatile("s_barrier" ::: "memory");
        if (it + 2 < NIT) STAGE96((it + 2) * 32, As0, Bs0);
        COMPUTE96(As1, Bs1);
    }
#undef STAGE96
#undef COMPUTE96

#pragma unroll
    for (int r = 0; r < 4; ++r) {
        int gm = bm + wave * 16 + quad * 4 + r;
        if (gm >= N_NODES) continue;
#pragma unroll
        for (int j = 0; j < 6; ++j) {
            int col = j * 16 + l16;
            int seg = col >> 5, cl = col & 31;
            float v = acc[j][r];
            if (seg == 0)      fs1[(size_t)gm * HD1 + cl] = v;
            else if (seg == 1) fd1[(size_t)gm * HD1 + cl] = v;
            else               out1[(size_t)gm * HD1 + cl] = v + b1f[cl];
        }
    }
}

// layer-1 attention + final linear fused, 8 nodes per 256-block.
__global__ __launch_bounds__(256) void att32e_final_kernel(
        const int* __restrict__ rowptr, const int* __restrict__ csre,
        const int* __restrict__ src, const float* __restrict__ fs1,
        const float* __restrict__ fd1, const void* __restrict__ a1,
        const float* __restrict__ out1g, const float* __restrict__ h3,
        const void* __restrict__ Wlin, const void* __restrict__ blin,
        void* __restrict__ out, const int* __restrict__ dflag) {
    int f32 = *dflag;
    int n = blockIdx.x * 8 + (threadIdx.x >> 5);
    int lane = threadIdx.x & 31;
    float fdn = fd1[(size_t)n * HD1 + lane];
    float a = ldin(a1, lane, f32);            // a1[h][o], lane = h*8+o
    float den = 0.f, acc = 0.f;
    int start = rowptr[n], end = rowptr[n + 1];
    for (int i = start; i < end; ++i) {
        int s = src[csre[i]];
        float fsv = fs1[(size_t)s * HD1 + lane];
        float x = fsv + fdn;
        x = x > 0.f ? x : 0.2f * x;
        float term = x * a;
        term += __shfl_xor(term, 1);
        term += __shfl_xor(term, 2);
        term += __shfl_xor(term, 4);          // head-wide logit (8 lanes/oct)
        float p = expf(term);
        den += p;
        acc += p * fsv;
    }
    float out1v = fmaxf(out1g[(size_t)n * HD1 + lane] + acc / fmaxf(den, 1e-9f), 0.f);
    float h3v = h3[(size_t)n * HD1 + lane];
    float partial[OUTF];
#pragma unroll
    for (int o = 0; o < OUTF; ++o)
        partial[o] = h3v * ldin(Wlin, (size_t)lane * OUTF + o, f32)
                   + out1v * ldin(Wlin, (size_t)(HD1 + lane) * OUTF + o, f32);
#pragma unroll
    for (int st = 1; st <= 16; st <<= 1)
#pragma unroll
        for (int o = 0; o < OUTF; ++o) partial[o] += __shfl_xor(partial[o], st);
    if (lane == 0) {
#pragma unroll
        for (int o = 0; o < OUTF; ++o) {
            float v = partial[o] + ldin(blin, o, f32);
            if (f32) ((float*)out)[(size_t)n * OUTF + o] = v;
            else     ((__hip_bfloat16*)out)[(size_t)n * OUTF + o] = __float2bfloat16(v);
        }
    }
}

// ---------------- launch ----------------
extern "C" void kernel_launch(void* const* d_in, const int* in_sizes, int n_in,
                              void* d_out, int out_size, void* d_ws, size_t ws_size,
                              hipStream_t stream) {
    const void* feats = d_in[0];
    const int*  src   = (const int*)d_in[1];
    const int*  dst   = (const int*)d_in[2];
    const void* tm    = d_in[3];
    const void* am    = d_in[4];
    const void* vm    = d_in[5];
    const void* W2    = d_in[6];
    const void* a2    = d_in[7];
    const void* Wl0   = d_in[8];
    const void* Wr0   = d_in[9];
    const void* a0    = d_in[10];
    const void* Wres0 = d_in[11];
    const void* b0    = d_in[12];
    const void* Wl1   = d_in[13];
    const void* Wr1   = d_in[14];
    const void* a1    = d_in[15];
    const void* Wres1 = d_in[16];
    const void* b1    = d_in[17];
    const void* Wlin  = d_in[18];
    const void* blin  = d_in[19];

    float* ws = (float*)d_ws;
    int*   dflag  = (int*)(ws + OFF_FLAG);
    float* colsum = ws + OFF_COLSUM;
    float* maskm  = ws + OFF_MASKM;
    float* z      = ws + OFF_Z;
    float* h3     = ws + OFF_H3;
    float* fs1    = ws + OFF_FS1;
    float* fd1    = ws + OFF_FD1;
    float* out1   = ws + OFF_OUT1;
    float* b0f    = ws + OFF_B0F;
    float* b1f    = ws + OFF_B1F;
    int*   deg    = (int*)(ws + OFF_DEG);
    int*   rowptr = (int*)(ws + OFF_ROWPTR);
    int*   cursor = (int*)(ws + OFF_CURSOR);
    int*   csre   = (int*)(ws + OFF_CSRE);
    __hip_bfloat16* out0r = (__hip_bfloat16*)(ws + OFF_OUT0);
    __hip_bfloat16* fs0b = (__hip_bfloat16*)(ws + OFF_FS0B);
    __hip_bfloat16* fd0b = (__hip_bfloat16*)(ws + OFF_FD0B);
    __hip_bfloat16* abf  = (__hip_bfloat16*)(ws + OFF_ABF);
    __hip_bfloat16* bt   = (__hip_bfloat16*)(ws + OFF_BT);
    __hip_bfloat16* bt1  = (__hip_bfloat16*)(ws + OFF_BT1);
    __hip_bfloat16* out0b = fd0b;   // fd0b row n retired after att0 block n reads it

    // single memset: dflag + colsum (contiguous). Other zeroing in init_kernel.
    (void)hipMemsetAsync(ws, 0, (16 + 1280) * sizeof(float), stream);

    // init: detect + deg-zero + bt-pad-zero (rows 3104..3327)
    init_kernel<<<664, 256, 0, stream>>>((const unsigned short*)feats, dflag, deg,
                                         (u32*)(bt + (size_t)(NBIG + HD1) * KPAD));
    // colsum + deg histogram + small preps
    prepA_kernel<<<455, 256, 0, stream>>>(feats, dst, tm, am, vm, b0, b1,
                                          colsum, deg, maskm, b0f, b1f, dflag);
    scan_kernel<<<1, 256, 0, stream>>>(deg, rowptr, cursor);
    scatter_kernel<<<(N_EDGES + 255) / 256, 256, 0, stream>>>(dst, cursor, csre);

    // big prep: A rows + all weight transposes
    prepB_kernel<<<MPAD + 3840 + 160 + 384, 256, 0, stream>>>(
        feats, colsum, maskm, abf, Wl0, Wr0, Wres0, W2, bt, Wl1, Wr1, Wres1, bt1, dflag);

    // big fused projection GEMM, 128x256 tiles, XCD-swizzled (1040 blocks)
    mfma_gemm<<<1040, 256, 0, stream>>>(
        (const unsigned short*)abf, (const unsigned short*)bt, b0f, fs0b, fd0b, out0r, z);

    // gat_inner attention (es/ed on the fly)
    att32z_kernel<<<N_NODES / 8, 256, 0, stream>>>(rowptr, csre, src, z, a2, h3, dflag);

    // GATv2 layer 0: fused single-pass attention
    att0_kernel<<<N_NODES, 256, 0, stream>>>(rowptr, csre, src, fs0b, fd0b, a0,
                                             out0r, out0b, dflag);

    // GATv2 layer 1 GEMM
    mfma_gemm96<<<(N_NODES + 63) / 64, 256, 0, stream>>>(
        (const unsigned short*)out0b, (const unsigned short*)bt1, b1f, fs1, fd1, out1);

    // layer-1 attention + final linear fused
    att32e_final_kernel<<<N_NODES / 8, 256, 0, stream>>>(
        rowptr, csre, src, fs1, fd1, a1, out1, h3, Wlin, blin, d_out, dflag);
}